// Round 2
// baseline (243.308 us; speedup 1.0000x reference)
//
#include <hip/hip_runtime.h>

// Problem dims (fixed by the reference):
#define BB 1024
#define AA 25
#define NN 250   // graph_size
#define PP 250   // patrol nodes
#define BA (BB * AA)     // 25600 rows
#define GROUPS 125       // 12-float output groups per row (250*6/12)
#define BLOCKS 1600      // 1600 blocks * 4 waves = 6400 waves -> 4 rows/wave
#define TPB 256

// Native vector types (HIP's float2/float4 are classes; these work with
// __builtin_nontemporal_* and lower to dwordx2/dwordx4).
typedef float v2f __attribute__((ext_vector_type(2)));
typedef float v4f __attribute__((ext_vector_type(4)));

// Wave-per-row, lane-per-12-float-group. No LDS, no barriers.
// Row ba: out[ba][n][0:3]=state, [3:5]=(zx,zy), [5]=adj[idx][n].
// Group g covers nodes n0=2g, 2g+1:
//   f4 #0: (st[6g+0], st[6g+1], st[6g+2], zx)
//   f4 #1: (zy, adj[2g], st[6g+3], st[6g+4])
//   f4 #2: (st[6g+5], zx, zy, adj[2g+1])
// Alignment: state row base = ba*3000B, +24g -> 8B-aligned (v2f ok).
//            adj row base = idx*1000B, +8g -> 8B-aligned (v2f ok).
//            out row base = ba*6000B, +48g -> 16B-aligned (v4f ok).
__global__ __launch_bounds__(TPB) void policy_kernel(
    const float* __restrict__ state,         // [BA, N*3]
    const float* __restrict__ nodes_coords,  // [P, 2]
    const float* __restrict__ adj,           // [P, N]
    const int*   __restrict__ nlv,           // [BA]
    const int*   __restrict__ patrol_index,  // [P]
    float* __restrict__ out)                 // [BA, N*6]
{
    const int tid    = threadIdx.x;
    const int lane   = tid & 63;
    const int wave   = (blockIdx.x << 2) | (tid >> 6);
    const int nwaves = BLOCKS << 2;  // 6400

    for (int ba = wave; ba < BA; ba += nwaves) {
        // Wave-uniform scalars (same-address loads broadcast; adj/nlv stay L2-hot).
        const int nv  = __builtin_amdgcn_readfirstlane(nlv[ba]);
        const int idx = __builtin_amdgcn_readfirstlane(patrol_index[nv]);
        const float zx = nodes_coords[2 * nv + 0];
        const float zy = nodes_coords[2 * nv + 1];

        const v2f* st2 = (const v2f*)(state + (size_t)ba * (NN * 3));
        const v2f* ad2 = (const v2f*)(adj + (size_t)idx * NN);
        v4f* op4 = (v4f*)(out + (size_t)ba * (NN * 6));

        for (int g = lane; g < GROUPS; g += 64) {
            // Streaming reads (read-once) -> nontemporal, keep L2 for adj.
            v2f s0 = __builtin_nontemporal_load(&st2[3 * g + 0]);
            v2f s1 = __builtin_nontemporal_load(&st2[3 * g + 1]);
            v2f s2 = __builtin_nontemporal_load(&st2[3 * g + 2]);
            v2f a  = ad2[g];  // reused across rows -> cached

            v4f v0 = {s0.x, s0.y, s1.x, zx};
            v4f v1 = {zy, a.x, s1.y, s2.x};
            v4f v2 = {s2.y, zx, zy, a.y};

            __builtin_nontemporal_store(v0, &op4[3 * g + 0]);
            __builtin_nontemporal_store(v1, &op4[3 * g + 1]);
            __builtin_nontemporal_store(v2, &op4[3 * g + 2]);
        }
    }
}

extern "C" void kernel_launch(void* const* d_in, const int* in_sizes, int n_in,
                              void* d_out, int out_size, void* d_ws, size_t ws_size,
                              hipStream_t stream) {
    const float* state        = (const float*)d_in[0];
    const float* nodes_coords = (const float*)d_in[1];
    const float* adj          = (const float*)d_in[2];
    const int*   nlv          = (const int*)d_in[3];
    const int*   patrol_index = (const int*)d_in[4];
    float* out = (float*)d_out;

    policy_kernel<<<dim3(BLOCKS), dim3(TPB), 0, stream>>>(
        state, nodes_coords, adj, nlv, patrol_index, out);
}

// Round 3
// 223.630 us; speedup vs baseline: 1.0880x; 1.0880x over previous
//
#include <hip/hip_runtime.h>

// Problem dims (fixed by the reference):
#define BB 1024
#define AA 25
#define NN 250   // graph_size
#define PP 250   // patrol nodes
#define BA (BB * AA)   // 25600 rows
#define TPB 256

typedef float v2f __attribute__((ext_vector_type(2)));
typedef float v4f __attribute__((ext_vector_type(4)));

// One block per TWO (b,a) rows. Stage both state rows (6000 B, 16B-aligned ->
// 375 dwordx4 loads) + both adj rows in LDS, then emit 750 contiguous float4
// stores. Every global load/store instruction is fully lane-contiguous.
//
// Output 12-float group g of a row (nodes n0=2g, 2g+1):
//   f4 #0: (st[6g+0], st[6g+1], st[6g+2], zx)
//   f4 #1: (zy, adj[2g], st[6g+3], st[6g+4])
//   f4 #2: (st[6g+5], zx, zy, adj[2g+1])
__global__ __launch_bounds__(TPB) void policy_kernel(
    const float* __restrict__ state,         // [BA, N*3]
    const float* __restrict__ nodes_coords,  // [P, 2]
    const float* __restrict__ adj,           // [P, N]
    const int*   __restrict__ nlv,           // [BA]
    const int*   __restrict__ patrol_index,  // [P]
    float* __restrict__ out)                 // [BA, N*6]
{
    __shared__ float s_state[2 * NN * 3];  // 6000 B
    __shared__ float s_adj[2 * NN];        // 2000 B
    __shared__ float s_z[4];               // zx0, zy0, zx1, zy1

    const int tid = threadIdx.x;
    const int ba0 = blockIdx.x * 2;

    // Stage state: 375 float4, fully coalesced, 16B-aligned base (ba0*3000B % 16 == 0).
    {
        const v4f* st4 = (const v4f*)(state + (size_t)ba0 * (NN * 3));
        v4f* ss4 = (v4f*)s_state;
        for (int i = tid; i < (2 * NN * 3) / 4; i += TPB)
            ss4[i] = st4[i];
    }

    // Stage adj rows + per-row scalars. Row r handled by half-wave group r.
    {
        const int r = tid >> 7;   // 0 or 1
        const int j = tid & 127;  // 0..127
        const int ba = ba0 + r;
        const int nv  = nlv[ba];            // uniform within the 128-thread group
        const int idx = patrol_index[nv];
        if (j == 0) {
            s_z[2 * r + 0] = nodes_coords[2 * nv + 0];
            s_z[2 * r + 1] = nodes_coords[2 * nv + 1];
        }
        const v2f* ad2 = (const v2f*)(adj + (size_t)idx * NN);  // 8B-aligned
        if (j < NN / 2)
            ((v2f*)(s_adj + r * NN))[j] = ad2[j];  // L2-hot (adj is 250 KB)
    }
    __syncthreads();

    const float zx0 = s_z[0], zy0 = s_z[1], zx1 = s_z[2], zy1 = s_z[3];

    // Emit 750 float4 = 3000 contiguous floats, 16B-aligned base.
    v4f* op4 = (v4f*)(out + (size_t)ba0 * (NN * 6));
    for (int q = tid; q < 2 * (NN * 6) / 4; q += TPB) {
        const int row = (q >= 375);
        const int ql  = q - 375 * row;
        const int g   = ql / 3;
        const int r   = ql - 3 * g;
        const float* sp = s_state + row * (NN * 3) + 6 * g;
        const float* ap = s_adj + row * NN + 2 * g;
        const float zx = row ? zx1 : zx0;
        const float zy = row ? zy1 : zy0;
        v4f v;
        if (r == 0) {
            v = (v4f){sp[0], sp[1], sp[2], zx};
        } else if (r == 1) {
            v = (v4f){zy, ap[0], sp[3], sp[4]};
        } else {
            v = (v4f){sp[5], zx, zy, ap[1]};
        }
        op4[q] = v;
    }
}

extern "C" void kernel_launch(void* const* d_in, const int* in_sizes, int n_in,
                              void* d_out, int out_size, void* d_ws, size_t ws_size,
                              hipStream_t stream) {
    const float* state        = (const float*)d_in[0];
    const float* nodes_coords = (const float*)d_in[1];
    const float* adj          = (const float*)d_in[2];
    const int*   nlv          = (const int*)d_in[3];
    const int*   patrol_index = (const int*)d_in[4];
    float* out = (float*)d_out;

    policy_kernel<<<dim3(BA / 2), dim3(TPB), 0, stream>>>(
        state, nodes_coords, adj, nlv, patrol_index, out);
}